// Round 8
// baseline (830.110 us; speedup 1.0000x reference)
//
#include <hip/hip_runtime.h>

typedef _Float16 f16;
typedef __attribute__((ext_vector_type(8))) _Float16 half8;
typedef __attribute__((ext_vector_type(4))) float f32x4;

struct f16x4 { f16 a, b, c, d; };

// frag-major layout for tensor[row][k] with K=512:
//   flat f16 idx = (rt*16 + kc)*512 + l*8 + e
//   row = rt*16 + (l&15), k = kc*32 + (l>>4)*8 + e

// async global->LDS, 16B per lane: dest = lds_base(wave-uniform) + lane*16,
// src = per-lane global pointer.
__device__ __forceinline__ void stage16(const f16* g, f16* l) {
  __builtin_amdgcn_global_load_lds(
      (const __attribute__((address_space(1))) void*)g,
      (__attribute__((address_space(3))) void*)l, 16, 0, 0);
}

// ---------------- fp32 -> frag-major f16 hi/lo split ----------------
__global__ void cvt_fr(const float* __restrict__ in, f16* __restrict__ hi,
                       f16* __restrict__ lo, int n_units) {
  const int u = blockIdx.x * blockDim.x + threadIdx.x;
  if (u >= n_units) return;
  const int l = u & 63, kc = (u >> 6) & 15, rt = u >> 10;
  const long ibase = (long)(rt * 16 + (l & 15)) * 512 + kc * 32 + ((l >> 4) << 3);
  const float4 v0 = *(const float4*)(in + ibase);
  const float4 v1 = *(const float4*)(in + ibase + 4);
  const float v[8] = {v0.x, v0.y, v0.z, v0.w, v1.x, v1.y, v1.z, v1.w};
  half8 h, lw;
#pragma unroll
  for (int e = 0; e < 8; ++e) {
    h[e] = (f16)v[e];
    lw[e] = (f16)(v[e] - (float)h[e]);
  }
  *(half8*)(hi + (long)u * 8) = h;
  *(half8*)(lo + (long)u * 8) = lw;
}

// ---------------- fp32 -> frag-major f16 (hi only) ----------------
__global__ void cvt_fr1(const float* __restrict__ in, f16* __restrict__ hi,
                        int n_units) {
  const int u = blockIdx.x * blockDim.x + threadIdx.x;
  if (u >= n_units) return;
  const int l = u & 63, kc = (u >> 6) & 15, rt = u >> 10;
  const long ibase = (long)(rt * 16 + (l & 15)) * 512 + kc * 32 + ((l >> 4) << 3);
  const float4 v0 = *(const float4*)(in + ibase);
  const float4 v1 = *(const float4*)(in + ibase + 4);
  const float v[8] = {v0.x, v0.y, v0.z, v0.w, v1.x, v1.y, v1.z, v1.w};
  half8 h;
#pragma unroll
  for (int e = 0; e < 8; ++e) h[e] = (f16)v[e];
  *(half8*)(hi + (long)u * 8) = h;
}

// ---------------- bias_sum[e] = sum_r msg_b[r,e] ----------------
__global__ void bias_sum_k(const float* __restrict__ msg_b, float* __restrict__ bs) {
  int e = threadIdx.x;  // 512 threads
  float s = 0.f;
  for (int r = 0; r < 8; ++r) s += msg_b[r * 512 + e];
  bs[e] = s;
}

// ============ 8-phase 256x256 split-f16 MFMA GEMM (T3+T4+T5, frag-major) ============
// C = sum_{r,k} A_r B_r^T; per-wave 128x64 (acc[8][4]); 8 waves (2M x 4N).
// LDS: 3 x 48KB tile buffers (triple-buffer => tile t+2 stages DURING tile t,
// per-wave quota {2,2,1,1} across 4 phases). vmcnt(6) only at tile entry.
// Phase: {stage quota || ds_read mt-pair -> s_barrier -> lgkmcnt(0) ->
//         sched_barrier -> setprio(1) -> 16 MFMA -> setprio(0) -> s_barrier}.
// SPL=1: A split (units[32..47]=A-lo); SPL=0: B split (units[32..47]=B-lo).
// Unit map: [0..15]=A-hi row-tiles, [16..31]=B-hi col-tiles.
// Output: frag-major f16 hi/lo pair (Chi/Clo), LDS re-staged in 128-row halves.
template <int SPL>
__global__ __launch_bounds__(512, 2) void gemm_8ph(
    const f16* __restrict__ Ah, const f16* __restrict__ Lo,
    const f16* __restrict__ Bh, f16* __restrict__ Chi, f16* __restrict__ Clo,
    int NIT, long sAr, int zdiv, int zpx,
    long sAzr, long sAzb, long sBzr, long sBzb, long sCzr, long sCzb) {
  __shared__ __align__(16) f16 smem[73728];  // 3 x 24576 f16; epilogue uses 32768
  const int tid = threadIdx.x;
  const int lane = tid & 63;
  const int w = tid >> 6;          // 0..7
  const int wr = w & 1;            // M half (rows wr*128..)
  const int wc = w >> 1;           // 0..3 (cols wc*64..)
  // XCD swizzle: the 4 tiles of one z contiguous on one XCD
  const int l = blockIdx.x;
  const int xcd = l & 7, g = l >> 3;
  const int z = xcd * zpx + (g >> 2), t4 = g & 3;
  const int bx = t4 & 1, by = t4 >> 1;
  const int zr = z % zdiv, zb = z / zdiv;

  const f16* Ab = Ah + (long)zr * sAzr + (long)zb * sAzb + (long)by * 131072 + lane * 8;
  const f16* Bb = Bh + (long)zr * sBzr + (long)zb * sBzb + (long)bx * 131072 + lane * 8;
  const f16* Lb = SPL ? (Lo + (Ab - Ah)) : (Lo + (Bb - Bh));
  const long cbase = (long)zr * sCzr + (long)zb * sCzb;

  // per-wave staging sources: units s = w*6+q
  const f16* sp[6];
  int so[6];
#pragma unroll
  for (int q = 0; q < 6; ++q) {
    const int s = w * 6 + q;
    so[q] = s * 512;
    sp[q] = (s < 16) ? (Ab + (long)s * 8192)
          : (s < 32) ? (Bb + (long)(s - 16) * 8192)
                     : (Lb + (long)(s - 32) * 8192);
  }

  f32x4 acc[8][4];
#pragma unroll
  for (int i = 0; i < 8; ++i)
#pragma unroll
    for (int j = 0; j < 4; ++j) acc[i][j] = (f32x4){0.f, 0.f, 0.f, 0.f};

  auto KOFF = [&](int ii) { return (long)(ii >> 4) * sAr + (long)(ii & 15) * 512; };

  // prologue: stage tiles 0,1
#pragma unroll
  for (int q = 0; q < 6; ++q) stage16(sp[q] + KOFF(0), &smem[so[q]]);
  {
    const long k1 = KOFF(1);
#pragma unroll
    for (int q = 0; q < 6; ++q) stage16(sp[q] + k1, &smem[24576 + so[q]]);
  }

  int cur = 0;
  const int lo8 = lane * 8;
  for (int t = 0; t < NIT; ++t) {
    // tile entry: drain oldest tile's 6 DMAs (mine), keep next tile in flight
    if (t < NIT - 1) asm volatile("s_waitcnt vmcnt(6)" ::: "memory");
    else             asm volatile("s_waitcnt vmcnt(0)" ::: "memory");
    __builtin_amdgcn_s_barrier();            // all waves drained => tile visible
    __builtin_amdgcn_sched_barrier(0);
    const f16* lb = &smem[cur * 24576];
    const bool st = (t + 2 < NIT);
    int nb = cur + 2; if (nb >= 3) nb -= 3;
    f16* nd = &smem[nb * 24576];
    const long nkk = KOFF(st ? t + 2 : 0);
    half8 bh[4], bl[4];
#pragma unroll
    for (int nt = 0; nt < 4; ++nt) {
      bh[nt] = *(const half8*)(lb + (16 + wc * 4 + nt) * 512 + lo8);
      if constexpr (!SPL)
        bl[nt] = *(const half8*)(lb + (32 + wc * 4 + nt) * 512 + lo8);
    }
#pragma unroll
    for (int p = 0; p < 4; ++p) {
      const int m0 = p * 2;
      if (st) {  // stage quota for tile t+2 into buf (t+2)%3
        if (p == 0)      { stage16(sp[0] + nkk, nd + so[0]); stage16(sp[1] + nkk, nd + so[1]); }
        else if (p == 1) { stage16(sp[2] + nkk, nd + so[2]); stage16(sp[3] + nkk, nd + so[3]); }
        else if (p == 2) { stage16(sp[4] + nkk, nd + so[4]); }
        else             { stage16(sp[5] + nkk, nd + so[5]); }
      }
      half8 a0 = *(const half8*)(lb + (wr * 8 + m0) * 512 + lo8);
      half8 a1 = *(const half8*)(lb + (wr * 8 + m0 + 1) * 512 + lo8);
      half8 l0, l1;
      if constexpr (SPL) {
        l0 = *(const half8*)(lb + (32 + wr * 8 + m0) * 512 + lo8);
        l1 = *(const half8*)(lb + (32 + wr * 8 + m0 + 1) * 512 + lo8);
      }
      __builtin_amdgcn_s_barrier();          // phase alignment across waves
      asm volatile("s_waitcnt lgkmcnt(0)" ::: "memory");
      __builtin_amdgcn_sched_barrier(0);
      __builtin_amdgcn_s_setprio(1);
#pragma unroll
      for (int nt = 0; nt < 4; ++nt) {
        acc[m0][nt] = __builtin_amdgcn_mfma_f32_16x16x32_f16(a0, bh[nt], acc[m0][nt], 0, 0, 0);
        if constexpr (!SPL)
          acc[m0][nt] = __builtin_amdgcn_mfma_f32_16x16x32_f16(a0, bl[nt], acc[m0][nt], 0, 0, 0);
        else
          acc[m0][nt] = __builtin_amdgcn_mfma_f32_16x16x32_f16(l0, bh[nt], acc[m0][nt], 0, 0, 0);
      }
#pragma unroll
      for (int nt = 0; nt < 4; ++nt) {
        acc[m0 + 1][nt] = __builtin_amdgcn_mfma_f32_16x16x32_f16(a1, bh[nt], acc[m0 + 1][nt], 0, 0, 0);
        if constexpr (!SPL)
          acc[m0 + 1][nt] = __builtin_amdgcn_mfma_f32_16x16x32_f16(a1, bl[nt], acc[m0 + 1][nt], 0, 0, 0);
        else
          acc[m0 + 1][nt] = __builtin_amdgcn_mfma_f32_16x16x32_f16(l1, bh[nt], acc[m0 + 1][nt], 0, 0, 0);
      }
      __builtin_amdgcn_s_setprio(0);
      __builtin_amdgcn_s_barrier();
    }
    cur = cur + 1; if (cur >= 3) cur -= 3;
  }
  __syncthreads();  // full drain before epilogue smem reuse

  // ---- epilogue: 256x256 C in two 128-row halves; hi pass then lo pass ----
  // C/D layout: col = lane&15, row = (lane>>4)*4 + v  [m89-verified]
  const int l15 = lane & 15;
  const int rb = (lane >> 4) << 2;
#pragma unroll
  for (int h = 0; h < 2; ++h) {
    // hi write (waves of this half), turning acc into residual
    if (wr == h) {
#pragma unroll
      for (int nt = 0; nt < 4; ++nt) {
        const int col = wc * 64 + nt * 16 + l15;
        const int ch = col >> 7, cl = col & 127;
#pragma unroll
        for (int mt = 0; mt < 8; ++mt)
#pragma unroll
          for (int v = 0; v < 4; ++v) {
            const int row = mt * 16 + rb + v;  // local row within half
            const float cval = acc[mt][nt][v];
            const f16 hh = (f16)cval;
            smem[row * 256 + ch * 128 + (((cl >> 3) ^ (row & 15)) << 3) + (cl & 7)] = hh;
            acc[mt][nt][v] = cval - (float)hh;
          }
      }
    }
    __syncthreads();
#pragma unroll
    for (int i2 = 0; i2 < 8; ++i2) {
      const int u = i2 * 512 + tid;
      const int ul = u & 63, kc_loc = (u >> 6) & 7, rt8 = u >> 9;
      const int row = rt8 * 16 + (ul & 15);
      const int gc = kc_loc * 4 + (ul >> 4);
      const int ch = gc >> 4, cl8 = gc & 15;
      const int4 vv = *(const int4*)&smem[row * 256 + ch * 128 + ((cl8 ^ (row & 15)) << 3)];
      const long unit = (long)((by * 16 + h * 8 + rt8) * 16 + bx * 8 + kc_loc);
      *(int4*)&Chi[cbase + unit * 512 + ul * 8] = vv;
    }
    __syncthreads();
    // lo write
    if (wr == h) {
#pragma unroll
      for (int nt = 0; nt < 4; ++nt) {
        const int col = wc * 64 + nt * 16 + l15;
        const int ch = col >> 7, cl = col & 127;
#pragma unroll
        for (int mt = 0; mt < 8; ++mt)
#pragma unroll
          for (int v = 0; v < 4; ++v) {
            const int row = mt * 16 + rb + v;
            smem[row * 256 + ch * 128 + (((cl >> 3) ^ (row & 15)) << 3) + (cl & 7)] =
                (f16)acc[mt][nt][v];
          }
      }
    }
    __syncthreads();
#pragma unroll
    for (int i2 = 0; i2 < 8; ++i2) {
      const int u = i2 * 512 + tid;
      const int ul = u & 63, kc_loc = (u >> 6) & 7, rt8 = u >> 9;
      const int row = rt8 * 16 + (ul & 15);
      const int gc = kc_loc * 4 + (ul >> 4);
      const int ch = gc >> 4, cl8 = gc & 15;
      const int4 vv = *(const int4*)&smem[row * 256 + ch * 128 + ((cl8 ^ (row & 15)) << 3)];
      const long unit = (long)((by * 16 + h * 8 + rt8) * 16 + bx * 8 + kc_loc);
      *(int4*)&Clo[cbase + unit * 512 + ul * 8] = vv;
    }
    __syncthreads();
  }
}

// ---------------- LDS-staged split-f16 MFMA GEMM (m97 + counted-vmcnt T4) ----------------
// Retained for G3/G4 (fp32 linear out). 128x128 tile, 4 waves 2x2.
template <int SA, int SB, int OUT, int SWZ>
__global__ __launch_bounds__(256, 3) void gemm_dr(
    const f16* __restrict__ Ah, const f16* __restrict__ Al,
    const f16* __restrict__ Bh, const f16* __restrict__ Bl,
    f16* __restrict__ Chi, f16* __restrict__ Clo, float* __restrict__ Cf,
    const float* __restrict__ bias, int N, int R, long sAr, long sBr,
    int zdiv, long sAzr, long sAzb, long sBzr, long sBzb,
    long sCzr, long sCzb) {
  constexpr int NU = 8 * ((1 + SA) + (1 + SB));
  constexpr int NW = NU / 4;
  constexpr int BUF = NU * 512;
  constexpr int SMEMN = (2 * BUF > 16384) ? 2 * BUF : 16384;
  __shared__ __align__(16) f16 smem[SMEMN];

  const int tid = threadIdx.x;
  int bx, by, z;
  if constexpr (SWZ) {
    const int l = blockIdx.x;
    const int xcd = l & 7, m2 = l >> 3, zq = m2 >> 4, t = m2 & 15;
    z = (zq << 3) | xcd; bx = t & 3; by = t >> 2;
  } else {
    bx = blockIdx.x; by = blockIdx.y; z = blockIdx.z;
  }
  const int zr = z % zdiv, zb = z / zdiv;
  const int lane = tid & 63;
  const int w = tid >> 6;
  const int wm = (w & 1) << 6;
  const int wn = (w >> 1) << 6;

  const f16* gA = Ah + (long)zr * sAzr + (long)zb * sAzb + (long)by * 65536 + lane * 8;
  const f16* gB = Bh + (long)zr * sBzr + (long)zb * sBzb + (long)bx * 65536 + lane * 8;
  const f16* gAl = SA ? (Al + (gA - Ah)) : nullptr;
  const f16* gBl = SB ? (Bl + (gB - Bh)) : nullptr;
  const long cbase = (long)zr * sCzr + (long)zb * sCzb;

  f32x4 acc[4][4];
#pragma unroll
  for (int i = 0; i < 4; ++i)
#pragma unroll
    for (int j = 0; j < 4; ++j) acc[i][j] = (f32x4){0.f, 0.f, 0.f, 0.f};

  const int NIT = R * 16;

  auto ST = [&](int bf, int ii) {
    const long oa = (long)(ii >> 4) * sAr + (ii & 15) * 512;
    const long ob = (long)(ii >> 4) * sBr + (ii & 15) * 512;
    f16* lb = &smem[bf * BUF];
#pragma unroll
    for (int q = 0; q < NW; ++q) {
      const int s = w * NW + q;
      const f16* src;
      if (s < 8) {
        src = gA + (long)s * 8192 + oa;
      } else if (SA && s < 16) {
        src = gAl + (long)(s - 8) * 8192 + oa;
      } else {
        const int sb = s - 8 * (1 + SA);
        src = (SB && sb >= 8) ? (gBl + (long)(sb - 8) * 8192 + ob)
                              : (gB + (long)sb * 8192 + ob);
      }
      stage16(src, lb + s * 512);
    }
  };

  auto CP = [&](int bf) {
    const f16* lb = &smem[bf * BUF];
    const int lo8 = lane * 8;
    half8 bh[4], bl[4];
#pragma unroll
    for (int nt = 0; nt < 4; ++nt) {
      const int ub = 8 * (1 + SA) + (w >> 1) * 4 + nt;
      bh[nt] = *(const half8*)(lb + ub * 512 + lo8);
      if constexpr (SB) bl[nt] = *(const half8*)(lb + (ub + 8) * 512 + lo8);
    }
#pragma unroll
    for (int mt = 0; mt < 4; ++mt) {
      const int ua = (w & 1) * 4 + mt;
      const half8 ah = *(const half8*)(lb + ua * 512 + lo8);
      half8 al;
      if constexpr (SA) al = *(const half8*)(lb + (ua + 8) * 512 + lo8);
#pragma unroll
      for (int nt = 0; nt < 4; ++nt) {
        acc[mt][nt] = __builtin_amdgcn_mfma_f32_16x16x32_f16(
            ah, bh[nt], acc[mt][nt], 0, 0, 0);
        if constexpr (SB)
          acc[mt][nt] = __builtin_amdgcn_mfma_f32_16x16x32_f16(
              ah, bl[nt], acc[mt][nt], 0, 0, 0);
        if constexpr (SA)
          acc[mt][nt] = __builtin_amdgcn_mfma_f32_16x16x32_f16(
              al, bh[nt], acc[mt][nt], 0, 0, 0);
      }
    }
  };

  auto WAITN = [&]() {
    if constexpr (NW == 4)      asm volatile("s_waitcnt vmcnt(4)" ::: "memory");
    else if constexpr (NW == 6) asm volatile("s_waitcnt vmcnt(6)" ::: "memory");
    else if constexpr (NW == 8) asm volatile("s_waitcnt vmcnt(8)" ::: "memory");
    else                        asm volatile("s_waitcnt vmcnt(0)" ::: "memory");
  };

  ST(0, 0);
  ST(1, 1);
  int cur = 0;
  for (int t = 0; t < NIT; ++t) {
    if (t < NIT - 1) WAITN();
    else asm volatile("s_waitcnt vmcnt(0)" ::: "memory");
    __builtin_amdgcn_s_barrier();
    __builtin_amdgcn_sched_barrier(0);
    CP(cur);
    asm volatile("s_waitcnt lgkmcnt(0)" ::: "memory");
    __builtin_amdgcn_s_barrier();
    if (t + 2 < NIT) ST(cur, t + 2);
    cur ^= 1;
  }
  __syncthreads();

  const int l15 = lane & 15;
  const int rb = (lane >> 4) << 2;
  if constexpr (OUT) {
#pragma unroll
    for (int nt = 0; nt < 4; ++nt) {
      const int col = wn + nt * 16 + l15;
#pragma unroll
      for (int mt = 0; mt < 4; ++mt)
#pragma unroll
        for (int v = 0; v < 4; ++v) {
          const int row = wm + mt * 16 + rb + v;
          const float cval = acc[mt][nt][v];
          const f16 h = (f16)cval;
          smem[row * 128 + ((col >> 3) ^ (row & 15)) * 8 + (col & 7)] = h;
          acc[mt][nt][v] = cval - (float)h;
        }
    }
    __syncthreads();
#pragma unroll
    for (int i2 = 0; i2 < 8; ++i2) {
      const int u = i2 * 256 + tid;
      const int ul = u & 63, kc_loc = (u >> 6) & 3, rt_loc = u >> 8;
      const int row = rt_loc * 16 + (ul & 15);
      const int gcol = kc_loc * 4 + (ul >> 4);
      const int4 vv = *(const int4*)&smem[row * 128 + ((gcol ^ (row & 15)) << 3)];
      *(int4*)&Chi[cbase + ((long)(by * 8 + rt_loc) * 16 + bx * 4 + kc_loc) * 512 + ul * 8] = vv;
    }
    __syncthreads();
#pragma unroll
    for (int nt = 0; nt < 4; ++nt) {
      const int col = wn + nt * 16 + l15;
#pragma unroll
      for (int mt = 0; mt < 4; ++mt)
#pragma unroll
        for (int v = 0; v < 4; ++v) {
          const int row = wm + mt * 16 + rb + v;
          smem[row * 128 + ((col >> 3) ^ (row & 15)) * 8 + (col & 7)] = (f16)acc[mt][nt][v];
        }
    }
    __syncthreads();
#pragma unroll
    for (int i2 = 0; i2 < 8; ++i2) {
      const int u = i2 * 256 + tid;
      const int ul = u & 63, kc_loc = (u >> 6) & 3, rt_loc = u >> 8;
      const int row = rt_loc * 16 + (ul & 15);
      const int gcol = kc_loc * 4 + (ul >> 4);
      const int4 vv = *(const int4*)&smem[row * 128 + ((gcol ^ (row & 15)) << 3)];
      *(int4*)&Clo[cbase + ((long)(by * 8 + rt_loc) * 16 + bx * 4 + kc_loc) * 512 + ul * 8] = vv;
    }
  } else {
#pragma unroll
    for (int nt = 0; nt < 4; ++nt) {
      const int col = bx * 128 + wn + nt * 16 + l15;
      const float bv = bias ? bias[col] : 0.f;
#pragma unroll
      for (int mt = 0; mt < 4; ++mt) {
        const long rowbase = (long)(by * 128 + wm + mt * 16 + rb) * N + col;
#pragma unroll
        for (int v = 0; v < 4; ++v)
          Cf[cbase + rowbase + (long)v * N] = acc[mt][nt][v] + bv;
      }
    }
  }
}

// ---------------- split-K x4 reduce (frag-major): agg = sum_q(Phi+Plo)+bsum ----------------
__global__ void reduce_agg4(const f16* __restrict__ Phi, const f16* __restrict__ Plo,
                            const float* __restrict__ bsum,
                            f16* __restrict__ hi, f16* __restrict__ lo) {
  const long i = ((long)blockIdx.x * blockDim.x + threadIdx.x) * 4;  // 4096x256 blocks
  const int li = (int)i;
  const int l = (li >> 3) & 63, kc = (li >> 9) & 15;
  const int e0 = kc * 32 + ((l >> 4) << 3) + (li & 4);
  const float4 b = *(const float4*)(bsum + e0);
  float v0 = b.x, v1 = b.y, v2 = b.z, v3 = b.w;
#pragma unroll
  for (int q = 0; q < 4; ++q) {
    const long o = (long)q * 4194304 + i;
    const f16x4 ph = *(const f16x4*)(Phi + o);
    const f16x4 pl = *(const f16x4*)(Plo + o);
    v0 += (float)ph.a + (float)pl.a;
    v1 += (float)ph.b + (float)pl.b;
    v2 += (float)ph.c + (float)pl.c;
    v3 += (float)ph.d + (float)pl.d;
  }
  f16x4 h, lw;
  h.a = (f16)v0; lw.a = (f16)(v0 - (float)h.a);
  h.b = (f16)v1; lw.b = (f16)(v1 - (float)h.b);
  h.c = (f16)v2; lw.c = (f16)(v2 - (float)h.c);
  h.d = (f16)v3; lw.d = (f16)(v3 - (float)h.d);
  *(f16x4*)(hi + i) = h;
  *(f16x4*)(lo + i) = lw;
}

// ---------------- GRU elementwise (fp32 gates), h frag-major f16 ----------------
__global__ void gru_k(const float* __restrict__ gi, const float* __restrict__ gh,
                      const float* __restrict__ holdf, f16* __restrict__ hhi) {
  const int u = blockIdx.x * blockDim.x + threadIdx.x;  // 524288 threads
  const int row = u >> 6, d0 = (u & 63) << 3;
  const long gbase = (long)row * 1536 + d0;
  const float4 giR0 = *(const float4*)(gi + gbase),      giR1 = *(const float4*)(gi + gbase + 4);
  const float4 giZ0 = *(const float4*)(gi + gbase + 512), giZ1 = *(const float4*)(gi + gbase + 516);
  const float4 giN0 = *(const float4*)(gi + gbase + 1024), giN1 = *(const float4*)(gi + gbase + 1028);
  const float4 ghR0 = *(const float4*)(gh + gbase),      ghR1 = *(const float4*)(gh + gbase + 4);
  const float4 ghZ0 = *(const float4*)(gh + gbase + 512), ghZ1 = *(const float4*)(gh + gbase + 516);
  const float4 ghN0 = *(const float4*)(gh + gbase + 1024), ghN1 = *(const float4*)(gh + gbase + 1028);
  const float irv[8] = {giR0.x, giR0.y, giR0.z, giR0.w, giR1.x, giR1.y, giR1.z, giR1.w};
  const float izv[8] = {giZ0.x, giZ0.y, giZ0.z, giZ0.w, giZ1.x, giZ1.y, giZ1.z, giZ1.w};
  const float inv[8] = {giN0.x, giN0.y, giN0.z, giN0.w, giN1.x, giN1.y, giN1.z, giN1.w};
  const float hrv[8] = {ghR0.x, ghR0.y, ghR0.z, ghR0.w, ghR1.x, ghR1.y, ghR1.z, ghR1.w};
  const float hzv[8] = {ghZ0.x, ghZ0.y, ghZ0.z, ghZ0.w, ghZ1.x, ghZ1.y, ghZ1.z, ghZ1.w};
  const float hnv[8] = {ghN0.x, ghN0.y, ghN0.z, ghN0.w, ghN1.x, ghN1.y, ghN1.z, ghN1.w};
  const long hflat = (long)(row >> 4) * 8192 + (d0 >> 5) * 512 +
                     ((row & 15) + (((d0 >> 3) & 3) << 4)) * 8;
  half8 hh8;
  if (!holdf) hh8 = *(const half8*)(hhi + hflat);
  half8 oh;
#pragma unroll
  for (int e = 0; e < 8; ++e) {
    const float h = holdf ? holdf[(long)row * 512 + d0 + e] : (float)hh8[e];
    const float r = 1.f / (1.f + __expf(-(irv[e] + hrv[e])));
    const float zg = 1.f / (1.f + __expf(-(izv[e] + hzv[e])));
    const float nt = tanhf(inv[e] + r * hnv[e]);
    const float o = (1.f - zg) * nt + zg * h;
    oh[e] = (f16)o;
  }
  *(half8*)(hhi + hflat) = oh;
}

// ---------------- mean over nodes (h frag-major) ----------------
__global__ void mean_k(const f16* __restrict__ hhi, float* __restrict__ out) {
  const int b = blockIdx.x;   // 16
  const int d = threadIdx.x;  // 512
  const long base = (long)b * 262144 + (d >> 5) * 512 + (((d >> 3) & 3) << 4) * 8 + (d & 7);
  float s = 0.f;
  for (int n = 0; n < 512; ++n) {
    const long j = base + (long)(n >> 4) * 8192 + (n & 15) * 8;
    s += (float)hhi[j];
  }
  out[b * 512 + d] = s * (1.f / 512.f);
}

extern "C" void kernel_launch(void* const* d_in, const int* in_sizes, int n_in,
                              void* d_out, int out_size, void* d_ws, size_t ws_size,
                              hipStream_t stream) {
  const float* nodes = (const float*)d_in[0];  // [16,512,512]
  const float* edges = (const float*)d_in[1];  // [16,8,512,512]
  const float* msg_W = (const float*)d_in[2];  // [8,512,512]
  const float* msg_b = (const float*)d_in[3];  // [8,512]
  const float* w_ih  = (const float*)d_in[4];  // [1536,512]
  const float* w_hh  = (const float*)d_in[5];  // [1536,512]
  const float* b_ih  = (const float*)d_in[6];  // [1536]
  const float* b_hh  = (const float*)d_in[7];  // [1536]
  float* out = (float*)d_out;                  // [16,512]

  char* ws = (char*)d_ws;
  size_t off = 0;
  auto alloc = [&](size_t bytes) -> char* {
    char* p = ws + off;
    off += (bytes + 1023) & ~(size_t)1023;
    return p;
  };
  f16* edges_hi = (f16*)alloc(33554432ull * 2);  // hi only (edges_lo dropped)
  f16* W_hi     = (f16*)alloc(2097152ull * 2);
  f16* W_lo     = (f16*)alloc(2097152ull * 2);
  f16* wih_hi   = (f16*)alloc(786432ull * 2);
  f16* whh_hi   = (f16*)alloc(786432ull * 2);
  f16* h_hi     = (f16*)alloc(4194304ull * 2);   // hi only (h_lo dropped)
  f16* hWT_hi   = (f16*)alloc(33554432ull * 2);  // head: gi fp32 after G3; tail: agg_hi/lo
  f16* hWT_lo   = (f16*)alloc(33554432ull * 2);  // head: gh fp32 after G4
  f16* Phi      = (f16*)alloc(16777216ull * 2);  // split-K x4 partial hi [q][b][frag-major]
  f16* Plo      = (f16*)alloc(16777216ull * 2);
  float* bsum   = (float*)alloc(512 * 4);
  float* gi = (float*)hWT_hi;                 // 50.33 MB
  float* gh = (float*)hWT_lo;                 // 50.33 MB
  f16* agg_hi = hWT_hi + 25165824;            // 8.39 MB
  f16* agg_lo = agg_hi + 4194304;             // 8.39 MB
  // total ws use ~205 MB

  // one-time frag-major converts
  cvt_fr1<<<16384, 256, 0, stream>>>(edges, edges_hi, 4194304);
  cvt_fr<<<1024,  256, 0, stream>>>(msg_W, W_hi, W_lo, 262144);
  cvt_fr1<<<384,  256, 0, stream>>>(w_ih, wih_hi, 98304);
  cvt_fr1<<<384,  256, 0, stream>>>(w_hh, whh_hi, 98304);
  cvt_fr1<<<2048, 256, 0, stream>>>(nodes, h_hi, 524288);
  bias_sum_k<<<1, 512, 0, stream>>>(msg_b, bsum);

  for (int step = 0; step < 2; ++step) {
    // G1: hWT[b*8+r][e,j] = sum_d W[r][e,d] * h[b][j,d]  -- 8-phase 256^2, split-A
    //     z = b*8+r (128 z, zdiv=8, zpx=16), 512 blocks
    gemm_8ph<1><<<512, 512, 0, stream>>>(
        W_hi, W_lo, h_hi, hWT_hi, hWT_lo,
        16, 0L, 8, 16, 262144L, 0L, 0L, 262144L, 262144L, 2097152L);
    // G2: split-K x4 (z = b*4+q, 64 z, zdiv=4, zpx=8), R=2 -- 8-phase 256^2, split-B
    gemm_8ph<0><<<256, 512, 0, stream>>>(
        edges_hi, hWT_lo, hWT_hi, Phi, Plo,
        32, 262144L, 4, 8, 524288L, 2097152L, 524288L, 2097152L, 4194304L, 262144L);
    // reduce: agg = sum_q (Phi+Plo) + bsum -> frag-major hi/lo
    reduce_agg4<<<4096, 256, 0, stream>>>(Phi, Plo, bsum, agg_hi, agg_lo);
    // G3: gi = agg @ w_ih^T + b_ih  (split-A, fp32 linear out)
    gemm_dr<1, 0, 0, 0><<<dim3(12, 64, 1), 256, 0, stream>>>(
        agg_hi, agg_lo, wih_hi, nullptr, nullptr, nullptr, gi, b_ih,
        1536, 1, 0L, 0L, 1, 0L, 0L, 0L, 0L, 0L, 0L);
    // G4: gh = h @ w_hh^T + b_hh  (single, fp32 linear out)
    gemm_dr<0, 0, 0, 0><<<dim3(12, 64, 1), 256, 0, stream>>>(
        h_hi, nullptr, whh_hi, nullptr, nullptr, nullptr, gh, b_hh,
        1536, 1, 0L, 0L, 1, 0L, 0L, 0L, 0L, 0L, 0L);
    // GRU update -> h_hi frag-major (in-place safe)
    gru_k<<<2048, 256, 0, stream>>>(gi, gh, step ? nullptr : nodes, h_hi);
  }
  mean_k<<<16, 512, 0, stream>>>(h_hi, out);
}

// Round 9
// 727.332 us; speedup vs baseline: 1.1413x; 1.1413x over previous
//
#include <hip/hip_runtime.h>

typedef _Float16 f16;
typedef __attribute__((ext_vector_type(8))) _Float16 half8;
typedef __attribute__((ext_vector_type(4))) float f32x4;

struct f16x4 { f16 a, b, c, d; };

// frag-major layout for tensor[row][k] with K=512:
//   flat f16 idx = (rt*16 + kc)*512 + l*8 + e
//   row = rt*16 + (l&15), k = kc*32 + (l>>4)*8 + e

// async global->LDS, 16B per lane: dest = lds_base(wave-uniform) + lane*16,
// src = per-lane global pointer.
__device__ __forceinline__ void stage16(const f16* g, f16* l) {
  __builtin_amdgcn_global_load_lds(
      (const __attribute__((address_space(1))) void*)g,
      (__attribute__((address_space(3))) void*)l, 16, 0, 0);
}

// ---------------- fp32 -> frag-major f16 hi/lo split ----------------
__global__ void cvt_fr(const float* __restrict__ in, f16* __restrict__ hi,
                       f16* __restrict__ lo, int n_units) {
  const int u = blockIdx.x * blockDim.x + threadIdx.x;
  if (u >= n_units) return;
  const int l = u & 63, kc = (u >> 6) & 15, rt = u >> 10;
  const long ibase = (long)(rt * 16 + (l & 15)) * 512 + kc * 32 + ((l >> 4) << 3);
  const float4 v0 = *(const float4*)(in + ibase);
  const float4 v1 = *(const float4*)(in + ibase + 4);
  const float v[8] = {v0.x, v0.y, v0.z, v0.w, v1.x, v1.y, v1.z, v1.w};
  half8 h, lw;
#pragma unroll
  for (int e = 0; e < 8; ++e) {
    h[e] = (f16)v[e];
    lw[e] = (f16)(v[e] - (float)h[e]);
  }
  *(half8*)(hi + (long)u * 8) = h;
  *(half8*)(lo + (long)u * 8) = lw;
}

// ---------------- fp32 -> frag-major f16 (hi only) ----------------
__global__ void cvt_fr1(const float* __restrict__ in, f16* __restrict__ hi,
                        int n_units) {
  const int u = blockIdx.x * blockDim.x + threadIdx.x;
  if (u >= n_units) return;
  const int l = u & 63, kc = (u >> 6) & 15, rt = u >> 10;
  const long ibase = (long)(rt * 16 + (l & 15)) * 512 + kc * 32 + ((l >> 4) << 3);
  const float4 v0 = *(const float4*)(in + ibase);
  const float4 v1 = *(const float4*)(in + ibase + 4);
  const float v[8] = {v0.x, v0.y, v0.z, v0.w, v1.x, v1.y, v1.z, v1.w};
  half8 h;
#pragma unroll
  for (int e = 0; e < 8; ++e) h[e] = (f16)v[e];
  *(half8*)(hi + (long)u * 8) = h;
}

// ---------------- bias_sum[e] = sum_r msg_b[r,e] ----------------
__global__ void bias_sum_k(const float* __restrict__ msg_b, float* __restrict__ bs) {
  int e = threadIdx.x;  // 512 threads
  float s = 0.f;
  for (int r = 0; r < 8; ++r) s += msg_b[r * 512 + e];
  bs[e] = s;
}

// ---------------- LDS-staged split-f16 MFMA GEMM (m97 + counted-vmcnt T4) ----------------
// C[m,n] = sum_{r,k} A_r[m,k]*B_r[n,k]; A,B frag-major (K=512/r-slice).
// acc += Ah*Bh [+Ah*Bl if SB] [+Al*Bh if SA]. 128x128 tile, 4 waves 2x2.
// K-loop: global_load_lds double-buffer staged 2 TILES AHEAD; raw s_barrier +
// counted s_waitcnt vmcnt(NW) (never 0 mid-loop) keep next tile's DMA in
// flight across the barrier -- the cp.async-style pipeline __syncthreads kills.
// OUT=1: Chi/Clo frag-major f16 pair (LDS-staged). OUT=0: Cf fp32 linear (+bias).
template <int SA, int SB, int OUT, int SWZ>
__global__ __launch_bounds__(256, 3) void gemm_dr(
    const f16* __restrict__ Ah, const f16* __restrict__ Al,
    const f16* __restrict__ Bh, const f16* __restrict__ Bl,
    f16* __restrict__ Chi, f16* __restrict__ Clo, float* __restrict__ Cf,
    const float* __restrict__ bias, int N, int R, long sAr, long sBr,
    int zdiv, long sAzr, long sAzb, long sBzr, long sBzb,
    long sCzr, long sCzb) {
  // staging units per k-step: 8x1KB A-hi (+8 A-lo if SA) + 8 B-hi (+8 B-lo if SB)
  constexpr int NU = 8 * ((1 + SA) + (1 + SB));
  constexpr int NW = NU / 4;          // units staged per wave (= vmcnt per tile)
  constexpr int BUF = NU * 512;       // f16 per buffer
  constexpr int SMEMN = (2 * BUF > 16384) ? 2 * BUF : 16384;
  __shared__ __align__(16) f16 smem[SMEMN];  // K-loop dbuf; epilogue re-stage aliases

  const int tid = threadIdx.x;
  int bx, by, z;
  if constexpr (SWZ) {
    const int l = blockIdx.x;
    const int xcd = l & 7, m2 = l >> 3, zq = m2 >> 4, t = m2 & 15;
    z = (zq << 3) | xcd; bx = t & 3; by = t >> 2;
  } else {
    bx = blockIdx.x; by = blockIdx.y; z = blockIdx.z;
  }
  const int zr = z % zdiv, zb = z / zdiv;
  const int lane = tid & 63;
  const int w = tid >> 6;
  const int wm = (w & 1) << 6;
  const int wn = (w >> 1) << 6;

  // block-level frag-major bases (per-lane 16B element included)
  const f16* gA = Ah + (long)zr * sAzr + (long)zb * sAzb + (long)by * 65536 + lane * 8;
  const f16* gB = Bh + (long)zr * sBzr + (long)zb * sBzb + (long)bx * 65536 + lane * 8;
  const f16* gAl = SA ? (Al + (gA - Ah)) : nullptr;
  const f16* gBl = SB ? (Bl + (gB - Bh)) : nullptr;
  const long cbase = (long)zr * sCzr + (long)zb * sCzb;

  f32x4 acc[4][4];
#pragma unroll
  for (int i = 0; i < 4; ++i)
#pragma unroll
    for (int j = 0; j < 4; ++j) acc[i][j] = (f32x4){0.f, 0.f, 0.f, 0.f};

  const int NIT = R * 16;

  // stage k-step ii into buffer bf (each wave issues NW async 1KB unit loads)
  auto ST = [&](int bf, int ii) {
    const long oa = (long)(ii >> 4) * sAr + (ii & 15) * 512;
    const long ob = (long)(ii >> 4) * sBr + (ii & 15) * 512;
    f16* lb = &smem[bf * BUF];
#pragma unroll
    for (int q = 0; q < NW; ++q) {
      const int s = w * NW + q;
      const f16* src;
      if (s < 8) {
        src = gA + (long)s * 8192 + oa;
      } else if (SA && s < 16) {
        src = gAl + (long)(s - 8) * 8192 + oa;
      } else {
        const int sb = s - 8 * (1 + SA);
        src = (SB && sb >= 8) ? (gBl + (long)(sb - 8) * 8192 + ob)
                              : (gB + (long)sb * 8192 + ob);
      }
      stage16(src, lb + s * 512);
    }
  };

  // compute k-step from buffer bf: ds_read_b128 fragments + MFMA
  auto CP = [&](int bf) {
    const f16* lb = &smem[bf * BUF];
    const int lo8 = lane * 8;
    half8 bh[4], bl[4];
#pragma unroll
    for (int nt = 0; nt < 4; ++nt) {
      const int ub = 8 * (1 + SA) + (w >> 1) * 4 + nt;
      bh[nt] = *(const half8*)(lb + ub * 512 + lo8);
      if constexpr (SB) bl[nt] = *(const half8*)(lb + (ub + 8) * 512 + lo8);
    }
#pragma unroll
    for (int mt = 0; mt < 4; ++mt) {
      const int ua = (w & 1) * 4 + mt;
      const half8 ah = *(const half8*)(lb + ua * 512 + lo8);
      half8 al;
      if constexpr (SA) al = *(const half8*)(lb + (ua + 8) * 512 + lo8);
#pragma unroll
      for (int nt = 0; nt < 4; ++nt) {
        acc[mt][nt] = __builtin_amdgcn_mfma_f32_16x16x32_f16(
            ah, bh[nt], acc[mt][nt], 0, 0, 0);
        if constexpr (SB)
          acc[mt][nt] = __builtin_amdgcn_mfma_f32_16x16x32_f16(
              ah, bl[nt], acc[mt][nt], 0, 0, 0);
        if constexpr (SA)
          acc[mt][nt] = __builtin_amdgcn_mfma_f32_16x16x32_f16(
              al, bh[nt], acc[mt][nt], 0, 0, 0);
      }
    }
  };

  // counted wait: keep newest tile's NW loads in flight, drain the oldest tile
  auto WAITN = [&]() {
    if constexpr (NW == 4)      asm volatile("s_waitcnt vmcnt(4)" ::: "memory");
    else if constexpr (NW == 6) asm volatile("s_waitcnt vmcnt(6)" ::: "memory");
    else if constexpr (NW == 8) asm volatile("s_waitcnt vmcnt(8)" ::: "memory");
    else                        asm volatile("s_waitcnt vmcnt(0)" ::: "memory");
  };

  // depth-2 pipeline: tiles t and t+1 in flight; per step:
  //   waitcnt(oldest) -> barrier -> CP -> lgkm(0) -> barrier -> ST(t+2)
  ST(0, 0);
  ST(1, 1);
  int cur = 0;
  for (int t = 0; t < NIT; ++t) {
    if (t < NIT - 1) WAITN();
    else asm volatile("s_waitcnt vmcnt(0)" ::: "memory");  // tail: <NW outstanding
    __builtin_amdgcn_s_barrier();           // whole tile t visible to all waves
    __builtin_amdgcn_sched_barrier(0);      // don't hoist ds_reads above barrier
    CP(cur);
    asm volatile("s_waitcnt lgkmcnt(0)" ::: "memory");  // my reads of buf done
    __builtin_amdgcn_s_barrier();           // everyone done reading buf[cur]
    if (t + 2 < NIT) ST(cur, t + 2);        // refill with tile t+2 (stays in flight)
    cur ^= 1;
  }
  __syncthreads();  // full drain before epilogue smem re-use

  // epilogue: C/D layout col = lane&15, row = (lane>>4)*4 + v  [m89-verified]
  const int l15 = lane & 15;
  const int rb = (lane >> 4) << 2;
  if constexpr (OUT) {
    // frag-major f16 hi/lo pair out via LDS re-stage (swizzle pg=(col>>3)^(row&15))
    // pass 1: hi (turn acc into residual)
#pragma unroll
    for (int nt = 0; nt < 4; ++nt) {
      const int col = wn + nt * 16 + l15;
#pragma unroll
      for (int mt = 0; mt < 4; ++mt)
#pragma unroll
        for (int v = 0; v < 4; ++v) {
          const int row = wm + mt * 16 + rb + v;
          const float cval = acc[mt][nt][v];
          const f16 h = (f16)cval;
          smem[row * 128 + ((col >> 3) ^ (row & 15)) * 8 + (col & 7)] = h;
          acc[mt][nt][v] = cval - (float)h;
        }
    }
    __syncthreads();
#pragma unroll
    for (int i2 = 0; i2 < 8; ++i2) {
      const int u = i2 * 256 + tid;
      const int ul = u & 63, kc_loc = (u >> 6) & 3, rt_loc = u >> 8;
      const int row = rt_loc * 16 + (ul & 15);
      const int gcol = kc_loc * 4 + (ul >> 4);
      const int4 vv = *(const int4*)&smem[row * 128 + ((gcol ^ (row & 15)) << 3)];
      *(int4*)&Chi[cbase + ((long)(by * 8 + rt_loc) * 16 + bx * 4 + kc_loc) * 512 + ul * 8] = vv;
    }
    __syncthreads();
    // pass 2: lo
#pragma unroll
    for (int nt = 0; nt < 4; ++nt) {
      const int col = wn + nt * 16 + l15;
#pragma unroll
      for (int mt = 0; mt < 4; ++mt)
#pragma unroll
        for (int v = 0; v < 4; ++v) {
          const int row = wm + mt * 16 + rb + v;
          smem[row * 128 + ((col >> 3) ^ (row & 15)) * 8 + (col & 7)] = (f16)acc[mt][nt][v];
        }
    }
    __syncthreads();
#pragma unroll
    for (int i2 = 0; i2 < 8; ++i2) {
      const int u = i2 * 256 + tid;
      const int ul = u & 63, kc_loc = (u >> 6) & 3, rt_loc = u >> 8;
      const int row = rt_loc * 16 + (ul & 15);
      const int gcol = kc_loc * 4 + (ul >> 4);
      const int4 vv = *(const int4*)&smem[row * 128 + ((gcol ^ (row & 15)) << 3)];
      *(int4*)&Clo[cbase + ((long)(by * 8 + rt_loc) * 16 + bx * 4 + kc_loc) * 512 + ul * 8] = vv;
    }
  } else {
    // fp32 direct output (linear rows x N)
#pragma unroll
    for (int nt = 0; nt < 4; ++nt) {
      const int col = bx * 128 + wn + nt * 16 + l15;
      const float bv = bias ? bias[col] : 0.f;
#pragma unroll
      for (int mt = 0; mt < 4; ++mt) {
        const long rowbase = (long)(by * 128 + wm + mt * 16 + rb) * N + col;
#pragma unroll
        for (int v = 0; v < 4; ++v)
          Cf[cbase + rowbase + (long)v * N] = acc[mt][nt][v] + bv;
      }
    }
  }
}

// ---------------- split-K x2 reduce (frag-major): agg = sum_q(Phi+Plo)+bsum ----------------
__global__ void reduce_agg2(const f16* __restrict__ Phi, const f16* __restrict__ Plo,
                            const float* __restrict__ bsum,
                            f16* __restrict__ hi, f16* __restrict__ lo) {
  const long i = ((long)blockIdx.x * blockDim.x + threadIdx.x) * 4;  // 4096x256 blocks
  const int li = (int)i;
  const int l = (li >> 3) & 63, kc = (li >> 9) & 15;
  const int e0 = kc * 32 + ((l >> 4) << 3) + (li & 4);
  const float4 b = *(const float4*)(bsum + e0);
  float v0 = b.x, v1 = b.y, v2 = b.z, v3 = b.w;
#pragma unroll
  for (int q = 0; q < 2; ++q) {
    const long o = (long)q * 4194304 + i;
    const f16x4 ph = *(const f16x4*)(Phi + o);
    const f16x4 pl = *(const f16x4*)(Plo + o);
    v0 += (float)ph.a + (float)pl.a;
    v1 += (float)ph.b + (float)pl.b;
    v2 += (float)ph.c + (float)pl.c;
    v3 += (float)ph.d + (float)pl.d;
  }
  f16x4 h, lw;
  h.a = (f16)v0; lw.a = (f16)(v0 - (float)h.a);
  h.b = (f16)v1; lw.b = (f16)(v1 - (float)h.b);
  h.c = (f16)v2; lw.c = (f16)(v2 - (float)h.c);
  h.d = (f16)v3; lw.d = (f16)(v3 - (float)h.d);
  *(f16x4*)(hi + i) = h;
  *(f16x4*)(lo + i) = lw;
}

// ---------------- GRU elementwise (fp32 gates), h frag-major f16 ----------------
__global__ void gru_k(const float* __restrict__ gi, const float* __restrict__ gh,
                      const float* __restrict__ holdf, f16* __restrict__ hhi) {
  const int u = blockIdx.x * blockDim.x + threadIdx.x;  // 524288 threads
  const int row = u >> 6, d0 = (u & 63) << 3;
  const long gbase = (long)row * 1536 + d0;
  const float4 giR0 = *(const float4*)(gi + gbase),      giR1 = *(const float4*)(gi + gbase + 4);
  const float4 giZ0 = *(const float4*)(gi + gbase + 512), giZ1 = *(const float4*)(gi + gbase + 516);
  const float4 giN0 = *(const float4*)(gi + gbase + 1024), giN1 = *(const float4*)(gi + gbase + 1028);
  const float4 ghR0 = *(const float4*)(gh + gbase),      ghR1 = *(const float4*)(gh + gbase + 4);
  const float4 ghZ0 = *(const float4*)(gh + gbase + 512), ghZ1 = *(const float4*)(gh + gbase + 516);
  const float4 ghN0 = *(const float4*)(gh + gbase + 1024), ghN1 = *(const float4*)(gh + gbase + 1028);
  const float irv[8] = {giR0.x, giR0.y, giR0.z, giR0.w, giR1.x, giR1.y, giR1.z, giR1.w};
  const float izv[8] = {giZ0.x, giZ0.y, giZ0.z, giZ0.w, giZ1.x, giZ1.y, giZ1.z, giZ1.w};
  const float inv[8] = {giN0.x, giN0.y, giN0.z, giN0.w, giN1.x, giN1.y, giN1.z, giN1.w};
  const float hrv[8] = {ghR0.x, ghR0.y, ghR0.z, ghR0.w, ghR1.x, ghR1.y, ghR1.z, ghR1.w};
  const float hzv[8] = {ghZ0.x, ghZ0.y, ghZ0.z, ghZ0.w, ghZ1.x, ghZ1.y, ghZ1.z, ghZ1.w};
  const float hnv[8] = {ghN0.x, ghN0.y, ghN0.z, ghN0.w, ghN1.x, ghN1.y, ghN1.z, ghN1.w};
  const long hflat = (long)(row >> 4) * 8192 + (d0 >> 5) * 512 +
                     ((row & 15) + (((d0 >> 3) & 3) << 4)) * 8;
  half8 hh8;
  if (!holdf) hh8 = *(const half8*)(hhi + hflat);
  half8 oh;
#pragma unroll
  for (int e = 0; e < 8; ++e) {
    const float h = holdf ? holdf[(long)row * 512 + d0 + e] : (float)hh8[e];
    const float r = 1.f / (1.f + __expf(-(irv[e] + hrv[e])));
    const float zg = 1.f / (1.f + __expf(-(izv[e] + hzv[e])));
    const float nt = tanhf(inv[e] + r * hnv[e]);
    const float o = (1.f - zg) * nt + zg * h;
    oh[e] = (f16)o;
  }
  *(half8*)(hhi + hflat) = oh;
}

// ---------------- mean over nodes (h frag-major) ----------------
__global__ void mean_k(const f16* __restrict__ hhi, float* __restrict__ out) {
  const int b = blockIdx.x;   // 16
  const int d = threadIdx.x;  // 512
  const long base = (long)b * 262144 + (d >> 5) * 512 + (((d >> 3) & 3) << 4) * 8 + (d & 7);
  float s = 0.f;
  for (int n = 0; n < 512; ++n) {
    const long j = base + (long)(n >> 4) * 8192 + (n & 15) * 8;
    s += (float)hhi[j];
  }
  out[b * 512 + d] = s * (1.f / 512.f);
}

extern "C" void kernel_launch(void* const* d_in, const int* in_sizes, int n_in,
                              void* d_out, int out_size, void* d_ws, size_t ws_size,
                              hipStream_t stream) {
  const float* nodes = (const float*)d_in[0];  // [16,512,512]
  const float* edges = (const float*)d_in[1];  // [16,8,512,512]
  const float* msg_W = (const float*)d_in[2];  // [8,512,512]
  const float* msg_b = (const float*)d_in[3];  // [8,512]
  const float* w_ih  = (const float*)d_in[4];  // [1536,512]
  const float* w_hh  = (const float*)d_in[5];  // [1536,512]
  const float* b_ih  = (const float*)d_in[6];  // [1536]
  const float* b_hh  = (const float*)d_in[7];  // [1536]
  float* out = (float*)d_out;                  // [16,512]

  char* ws = (char*)d_ws;
  size_t off = 0;
  auto alloc = [&](size_t bytes) -> char* {
    char* p = ws + off;
    off += (bytes + 1023) & ~(size_t)1023;
    return p;
  };
  f16* edges_hi = (f16*)alloc(33554432ull * 2);  // hi only (edges_lo dropped)
  f16* W_hi     = (f16*)alloc(2097152ull * 2);
  f16* W_lo     = (f16*)alloc(2097152ull * 2);
  f16* wih_hi   = (f16*)alloc(786432ull * 2);
  f16* whh_hi   = (f16*)alloc(786432ull * 2);
  f16* h_hi     = (f16*)alloc(4194304ull * 2);   // hi only (h_lo dropped)
  f16* hWT_hi   = (f16*)alloc(33554432ull * 2);  // head: gi fp32 after G3; tail: agg_hi/lo
  f16* hWT_lo   = (f16*)alloc(33554432ull * 2);  // head: gh fp32 after G4
  f16* Phi      = (f16*)alloc(16777216ull * 2);  // split-K x2 partial hi [q][b][frag-major]
  f16* Plo      = (f16*)alloc(16777216ull * 2);
  float* bsum   = (float*)alloc(512 * 4);
  float* gi = (float*)hWT_hi;                 // 50.33 MB
  float* gh = (float*)hWT_lo;                 // 50.33 MB
  f16* agg_hi = hWT_hi + 25165824;            // 8.39 MB
  f16* agg_lo = agg_hi + 4194304;             // 8.39 MB
  // total ws use ~205 MB

  // one-time frag-major converts
  cvt_fr1<<<16384, 256, 0, stream>>>(edges, edges_hi, 4194304);
  cvt_fr<<<1024,  256, 0, stream>>>(msg_W, W_hi, W_lo, 262144);
  cvt_fr1<<<384,  256, 0, stream>>>(w_ih, wih_hi, 98304);
  cvt_fr1<<<384,  256, 0, stream>>>(w_hh, whh_hi, 98304);
  cvt_fr1<<<2048, 256, 0, stream>>>(nodes, h_hi, 524288);
  bias_sum_k<<<1, 512, 0, stream>>>(msg_b, bsum);

  for (int step = 0; step < 2; ++step) {
    // G1: hWT[b*8+r][e,j] = sum_d W[r][e,d] * h[b][j,d]
    //     split-A (W hi/lo) x single-B (h hi); f16-pair out
    gemm_dr<1, 0, 1, 0><<<dim3(4, 4, 128), 256, 0, stream>>>(
        W_hi, W_lo, h_hi, nullptr, hWT_hi, hWT_lo, nullptr, nullptr,
        512, 1, 0L, 0L, 8, 262144L, 0L, 0L, 262144L, 262144L, 2097152L);
    // G2: split-K x2 (z = b*2+q), R=4, NIT=64; 512 blocks -> single uniform
    //     round at 3 blocks/CU (no 1/3-idle tail of the old 1024-block grid).
    //     single-A (edges hi) x split-B (hWT hi/lo); f16-pair partials out
    gemm_dr<0, 1, 1, 1><<<dim3(512, 1, 1), 256, 0, stream>>>(
        edges_hi, nullptr, hWT_hi, hWT_lo, Phi, Plo, nullptr, nullptr,
        512, 4, 262144L, 262144L, 2, 1048576L, 2097152L, 1048576L, 2097152L,
        4194304L, 262144L);
    // reduce: agg = sum_q (Phi+Plo) + bsum -> frag-major hi/lo  (q=2: 34 MB read)
    reduce_agg2<<<4096, 256, 0, stream>>>(Phi, Plo, bsum, agg_hi, agg_lo);
    // G3: gi = agg @ w_ih^T + b_ih  (split-A, fp32 linear out)
    gemm_dr<1, 0, 0, 0><<<dim3(12, 64, 1), 256, 0, stream>>>(
        agg_hi, agg_lo, wih_hi, nullptr, nullptr, nullptr, gi, b_ih,
        1536, 1, 0L, 0L, 1, 0L, 0L, 0L, 0L, 0L, 0L);
    // G4: gh = h @ w_hh^T + b_hh  (single, fp32 linear out)
    gemm_dr<0, 0, 0, 0><<<dim3(12, 64, 1), 256, 0, stream>>>(
        h_hi, nullptr, whh_hi, nullptr, nullptr, nullptr, gh, b_hh,
        1536, 1, 0L, 0L, 1, 0L, 0L, 0L, 0L, 0L, 0L);
    // GRU update -> h_hi frag-major (in-place safe)
    gru_k<<<2048, 256, 0, stream>>>(gi, gh, step ? nullptr : nodes, h_hi);
  }
  mean_k<<<16, 512, 0, stream>>>(h_hi, out);
}

// Round 11
// 684.962 us; speedup vs baseline: 1.2119x; 1.0619x over previous
//
#include <hip/hip_runtime.h>

typedef _Float16 f16;
typedef __attribute__((ext_vector_type(8))) _Float16 half8;
typedef __attribute__((ext_vector_type(4))) float f32x4;

struct f16x4 { f16 a, b, c, d; };

// frag-major layout for tensor[row][k] with K=512:
//   flat f16 idx = (rt*16 + kc)*512 + l*8 + e
//   row = rt*16 + (l&15), k = kc*32 + (l>>4)*8 + e

// async global->LDS, 16B per lane: dest = lds_base(wave-uniform) + lane*16,
// src = per-lane global pointer.
__device__ __forceinline__ void stage16(const f16* g, f16* l) {
  __builtin_amdgcn_global_load_lds(
      (const __attribute__((address_space(1))) void*)g,
      (__attribute__((address_space(3))) void*)l, 16, 0, 0);
}

// ---------------- fp32 -> frag-major f16 hi/lo split ----------------
__global__ void cvt_fr(const float* __restrict__ in, f16* __restrict__ hi,
                       f16* __restrict__ lo, int n_units) {
  const int u = blockIdx.x * blockDim.x + threadIdx.x;
  if (u >= n_units) return;
  const int l = u & 63, kc = (u >> 6) & 15, rt = u >> 10;
  const long ibase = (long)(rt * 16 + (l & 15)) * 512 + kc * 32 + ((l >> 4) << 3);
  const float4 v0 = *(const float4*)(in + ibase);
  const float4 v1 = *(const float4*)(in + ibase + 4);
  const float v[8] = {v0.x, v0.y, v0.z, v0.w, v1.x, v1.y, v1.z, v1.w};
  half8 h, lw;
#pragma unroll
  for (int e = 0; e < 8; ++e) {
    h[e] = (f16)v[e];
    lw[e] = (f16)(v[e] - (float)h[e]);
  }
  *(half8*)(hi + (long)u * 8) = h;
  *(half8*)(lo + (long)u * 8) = lw;
}

// ---------------- fp32 -> frag-major f16 (hi only) ----------------
__global__ void cvt_fr1(const float* __restrict__ in, f16* __restrict__ hi,
                        int n_units) {
  const int u = blockIdx.x * blockDim.x + threadIdx.x;
  if (u >= n_units) return;
  const int l = u & 63, kc = (u >> 6) & 15, rt = u >> 10;
  const long ibase = (long)(rt * 16 + (l & 15)) * 512 + kc * 32 + ((l >> 4) << 3);
  const float4 v0 = *(const float4*)(in + ibase);
  const float4 v1 = *(const float4*)(in + ibase + 4);
  const float v[8] = {v0.x, v0.y, v0.z, v0.w, v1.x, v1.y, v1.z, v1.w};
  half8 h;
#pragma unroll
  for (int e = 0; e < 8; ++e) h[e] = (f16)v[e];
  *(half8*)(hi + (long)u * 8) = h;
}

// ---------------- fused w_ih + w_hh converts (one launch) ----------------
__global__ void cvt_fr1_2(const float* __restrict__ inA, f16* __restrict__ hiA,
                          const float* __restrict__ inB, f16* __restrict__ hiB,
                          int nA) {
  int u = blockIdx.x * blockDim.x + threadIdx.x;
  const float* in = inA;
  f16* hi = hiA;
  if (u >= nA) { u -= nA; in = inB; hi = hiB; }
  const int l = u & 63, kc = (u >> 6) & 15, rt = u >> 10;
  const long ibase = (long)(rt * 16 + (l & 15)) * 512 + kc * 32 + ((l >> 4) << 3);
  const float4 v0 = *(const float4*)(in + ibase);
  const float4 v1 = *(const float4*)(in + ibase + 4);
  const float v[8] = {v0.x, v0.y, v0.z, v0.w, v1.x, v1.y, v1.z, v1.w};
  half8 h;
#pragma unroll
  for (int e = 0; e < 8; ++e) h[e] = (f16)v[e];
  *(half8*)(hi + (long)u * 8) = h;
}

// ---------------- bias_sum[e] = sum_r msg_b[r,e] ----------------
__global__ void bias_sum_k(const float* __restrict__ msg_b, float* __restrict__ bs) {
  int e = threadIdx.x;  // 512 threads
  float s = 0.f;
  for (int r = 0; r < 8; ++r) s += msg_b[r * 512 + e];
  bs[e] = s;
}

// ---------------- LDS-staged split-f16 MFMA GEMM (m97 + counted-vmcnt T4) ----------------
// C[m,n] = sum_{r,k} A_r[m,k]*B_r[n,k]; A,B frag-major (K=512/r-slice).
// acc += Ah*Bh [+Ah*Bl if SB] [+Al*Bh if SA]. 128x128 tile, 4 waves 2x2.
// K-loop: global_load_lds double-buffer staged 2 TILES AHEAD; raw s_barrier +
// counted s_waitcnt vmcnt(NW) (never 0 mid-loop) keep next tile's DMA in
// flight across the barrier. OUT=1: Chi/Clo frag-major f16 pair out.
template <int SA, int SB, int OUT, int SWZ>
__global__ __launch_bounds__(256, 3) void gemm_dr(
    const f16* __restrict__ Ah, const f16* __restrict__ Al,
    const f16* __restrict__ Bh, const f16* __restrict__ Bl,
    f16* __restrict__ Chi, f16* __restrict__ Clo, float* __restrict__ Cf,
    const float* __restrict__ bias, int N, int R, long sAr, long sBr,
    int zdiv, long sAzr, long sAzb, long sBzr, long sBzb,
    long sCzr, long sCzb) {
  constexpr int NU = 8 * ((1 + SA) + (1 + SB));
  constexpr int NW = NU / 4;          // units staged per wave (= vmcnt per tile)
  constexpr int BUF = NU * 512;       // f16 per buffer
  constexpr int SMEMN = (2 * BUF > 16384) ? 2 * BUF : 16384;
  __shared__ __align__(16) f16 smem[SMEMN];

  const int tid = threadIdx.x;
  int bx, by, z;
  if constexpr (SWZ) {
    const int l = blockIdx.x;
    const int xcd = l & 7, m2 = l >> 3, zq = m2 >> 4, t = m2 & 15;
    z = (zq << 3) | xcd; bx = t & 3; by = t >> 2;
  } else {
    bx = blockIdx.x; by = blockIdx.y; z = blockIdx.z;
  }
  const int zr = z % zdiv, zb = z / zdiv;
  const int lane = tid & 63;
  const int w = tid >> 6;
  const int wm = (w & 1) << 6;
  const int wn = (w >> 1) << 6;

  const f16* gA = Ah + (long)zr * sAzr + (long)zb * sAzb + (long)by * 65536 + lane * 8;
  const f16* gB = Bh + (long)zr * sBzr + (long)zb * sBzb + (long)bx * 65536 + lane * 8;
  const f16* gAl = SA ? (Al + (gA - Ah)) : nullptr;
  const f16* gBl = SB ? (Bl + (gB - Bh)) : nullptr;
  const long cbase = (long)zr * sCzr + (long)zb * sCzb;

  f32x4 acc[4][4];
#pragma unroll
  for (int i = 0; i < 4; ++i)
#pragma unroll
    for (int j = 0; j < 4; ++j) acc[i][j] = (f32x4){0.f, 0.f, 0.f, 0.f};

  const int NIT = R * 16;

  auto ST = [&](int bf, int ii) {
    const long oa = (long)(ii >> 4) * sAr + (ii & 15) * 512;
    const long ob = (long)(ii >> 4) * sBr + (ii & 15) * 512;
    f16* lb = &smem[bf * BUF];
#pragma unroll
    for (int q = 0; q < NW; ++q) {
      const int s = w * NW + q;
      const f16* src;
      if (s < 8) {
        src = gA + (long)s * 8192 + oa;
      } else if (SA && s < 16) {
        src = gAl + (long)(s - 8) * 8192 + oa;
      } else {
        const int sb = s - 8 * (1 + SA);
        src = (SB && sb >= 8) ? (gBl + (long)(sb - 8) * 8192 + ob)
                              : (gB + (long)sb * 8192 + ob);
      }
      stage16(src, lb + s * 512);
    }
  };

  auto CP = [&](int bf) {
    const f16* lb = &smem[bf * BUF];
    const int lo8 = lane * 8;
    half8 bh[4], bl[4];
#pragma unroll
    for (int nt = 0; nt < 4; ++nt) {
      const int ub = 8 * (1 + SA) + (w >> 1) * 4 + nt;
      bh[nt] = *(const half8*)(lb + ub * 512 + lo8);
      if constexpr (SB) bl[nt] = *(const half8*)(lb + (ub + 8) * 512 + lo8);
    }
#pragma unroll
    for (int mt = 0; mt < 4; ++mt) {
      const int ua = (w & 1) * 4 + mt;
      const half8 ah = *(const half8*)(lb + ua * 512 + lo8);
      half8 al;
      if constexpr (SA) al = *(const half8*)(lb + (ua + 8) * 512 + lo8);
#pragma unroll
      for (int nt = 0; nt < 4; ++nt) {
        acc[mt][nt] = __builtin_amdgcn_mfma_f32_16x16x32_f16(
            ah, bh[nt], acc[mt][nt], 0, 0, 0);
        if constexpr (SB)
          acc[mt][nt] = __builtin_amdgcn_mfma_f32_16x16x32_f16(
              ah, bl[nt], acc[mt][nt], 0, 0, 0);
        if constexpr (SA)
          acc[mt][nt] = __builtin_amdgcn_mfma_f32_16x16x32_f16(
              al, bh[nt], acc[mt][nt], 0, 0, 0);
      }
    }
  };

  auto WAITN = [&]() {
    if constexpr (NW == 4)      asm volatile("s_waitcnt vmcnt(4)" ::: "memory");
    else if constexpr (NW == 6) asm volatile("s_waitcnt vmcnt(6)" ::: "memory");
    else if constexpr (NW == 8) asm volatile("s_waitcnt vmcnt(8)" ::: "memory");
    else                        asm volatile("s_waitcnt vmcnt(0)" ::: "memory");
  };

  ST(0, 0);
  ST(1, 1);
  int cur = 0;
  for (int t = 0; t < NIT; ++t) {
    if (t < NIT - 1) WAITN();
    else asm volatile("s_waitcnt vmcnt(0)" ::: "memory");
    __builtin_amdgcn_s_barrier();
    __builtin_amdgcn_sched_barrier(0);
    CP(cur);
    asm volatile("s_waitcnt lgkmcnt(0)" ::: "memory");
    __builtin_amdgcn_s_barrier();
    if (t + 2 < NIT) ST(cur, t + 2);
    cur ^= 1;
  }
  __syncthreads();

  // epilogue: C/D layout col = lane&15, row = (lane>>4)*4 + v  [m89-verified]
  const int l15 = lane & 15;
  const int rb = (lane >> 4) << 2;
  if constexpr (OUT) {
#pragma unroll
    for (int nt = 0; nt < 4; ++nt) {
      const int col = wn + nt * 16 + l15;
#pragma unroll
      for (int mt = 0; mt < 4; ++mt)
#pragma unroll
        for (int v = 0; v < 4; ++v) {
          const int row = wm + mt * 16 + rb + v;
          const float cval = acc[mt][nt][v];
          const f16 h = (f16)cval;
          smem[row * 128 + ((col >> 3) ^ (row & 15)) * 8 + (col & 7)] = h;
          acc[mt][nt][v] = cval - (float)h;
        }
    }
    __syncthreads();
#pragma unroll
    for (int i2 = 0; i2 < 8; ++i2) {
      const int u = i2 * 256 + tid;
      const int ul = u & 63, kc_loc = (u >> 6) & 3, rt_loc = u >> 8;
      const int row = rt_loc * 16 + (ul & 15);
      const int gcol = kc_loc * 4 + (ul >> 4);
      const int4 vv = *(const int4*)&smem[row * 128 + ((gcol ^ (row & 15)) << 3)];
      *(int4*)&Chi[cbase + ((long)(by * 8 + rt_loc) * 16 + bx * 4 + kc_loc) * 512 + ul * 8] = vv;
    }
    __syncthreads();
#pragma unroll
    for (int nt = 0; nt < 4; ++nt) {
      const int col = wn + nt * 16 + l15;
#pragma unroll
      for (int mt = 0; mt < 4; ++mt)
#pragma unroll
        for (int v = 0; v < 4; ++v) {
          const int row = wm + mt * 16 + rb + v;
          smem[row * 128 + ((col >> 3) ^ (row & 15)) * 8 + (col & 7)] = (f16)acc[mt][nt][v];
        }
    }
    __syncthreads();
#pragma unroll
    for (int i2 = 0; i2 < 8; ++i2) {
      const int u = i2 * 256 + tid;
      const int ul = u & 63, kc_loc = (u >> 6) & 3, rt_loc = u >> 8;
      const int row = rt_loc * 16 + (ul & 15);
      const int gcol = kc_loc * 4 + (ul >> 4);
      const int4 vv = *(const int4*)&smem[row * 128 + ((gcol ^ (row & 15)) << 3)];
      *(int4*)&Clo[cbase + ((long)(by * 8 + rt_loc) * 16 + bx * 4 + kc_loc) * 512 + ul * 8] = vv;
    }
  } else {
#pragma unroll
    for (int nt = 0; nt < 4; ++nt) {
      const int col = bx * 128 + wn + nt * 16 + l15;
      const float bv = bias ? bias[col] : 0.f;
#pragma unroll
      for (int mt = 0; mt < 4; ++mt) {
        const long rowbase = (long)(by * 128 + wm + mt * 16 + rb) * N + col;
#pragma unroll
        for (int v = 0; v < 4; ++v)
          Cf[cbase + rowbase + (long)v * N] = acc[mt][nt][v] + bv;
      }
    }
  }
}

// ---------------- fused G3+G4 body: same pipeline, fp32 linear out, N=1536 ----------------
template <int SA>
__device__ __forceinline__ void gemm_body(
    const f16* __restrict__ Ah, const f16* __restrict__ Al,
    const f16* __restrict__ Bh, float* __restrict__ Cf,
    const float* __restrict__ bias, int bx, int by, f16* smem) {
  constexpr int NU = 8 * (1 + SA) + 8;     // A(+lo) + B units
  constexpr int NW = NU / 4;               // 6 (SA=1) or 4 (SA=0)
  constexpr int BUF = NU * 512;

  const int tid = threadIdx.x;
  const int lane = tid & 63;
  const int w = tid >> 6;
  const int wm = (w & 1) << 6;
  const int wn = (w >> 1) << 6;

  const f16* gA = Ah + (long)by * 65536 + lane * 8;
  const f16* gB = Bh + (long)bx * 65536 + lane * 8;
  const f16* gAl = SA ? (Al + (gA - Ah)) : nullptr;

  f32x4 acc[4][4];
#pragma unroll
  for (int i = 0; i < 4; ++i)
#pragma unroll
    for (int j = 0; j < 4; ++j) acc[i][j] = (f32x4){0.f, 0.f, 0.f, 0.f};

  auto ST = [&](int bf, int ii) {
    const long oa = (long)ii * 512;
    f16* lb = &smem[bf * BUF];
#pragma unroll
    for (int q = 0; q < NW; ++q) {
      const int s = w * NW + q;
      const f16* src;
      if (s < 8) src = gA + (long)s * 8192 + oa;
      else if (SA && s < 16) src = gAl + (long)(s - 8) * 8192 + oa;
      else src = gB + (long)(s - 8 * (1 + SA)) * 8192 + oa;
      stage16(src, lb + s * 512);
    }
  };
  auto CP = [&](int bf) {
    const f16* lb = &smem[bf * BUF];
    const int lo8 = lane * 8;
    half8 bh[4];
#pragma unroll
    for (int nt = 0; nt < 4; ++nt)
      bh[nt] = *(const half8*)(lb + (8 * (1 + SA) + (w >> 1) * 4 + nt) * 512 + lo8);
#pragma unroll
    for (int mt = 0; mt < 4; ++mt) {
      const int ua = (w & 1) * 4 + mt;
      const half8 ah = *(const half8*)(lb + ua * 512 + lo8);
      half8 al;
      if constexpr (SA) al = *(const half8*)(lb + (ua + 8) * 512 + lo8);
#pragma unroll
      for (int nt = 0; nt < 4; ++nt) {
        acc[mt][nt] = __builtin_amdgcn_mfma_f32_16x16x32_f16(ah, bh[nt], acc[mt][nt], 0, 0, 0);
        if constexpr (SA)
          acc[mt][nt] = __builtin_amdgcn_mfma_f32_16x16x32_f16(al, bh[nt], acc[mt][nt], 0, 0, 0);
      }
    }
  };
  auto WAITN = [&]() {
    if constexpr (NW == 4) asm volatile("s_waitcnt vmcnt(4)" ::: "memory");
    else                   asm volatile("s_waitcnt vmcnt(6)" ::: "memory");
  };

  ST(0, 0);
  ST(1, 1);
  int cur = 0;
  for (int t = 0; t < 16; ++t) {
    if (t < 15) WAITN();
    else asm volatile("s_waitcnt vmcnt(0)" ::: "memory");
    __builtin_amdgcn_s_barrier();
    __builtin_amdgcn_sched_barrier(0);
    CP(cur);
    asm volatile("s_waitcnt lgkmcnt(0)" ::: "memory");
    __builtin_amdgcn_s_barrier();
    if (t + 2 < 16) ST(cur, t + 2);
    cur ^= 1;
  }

  const int l15 = lane & 15;
  const int rb = (lane >> 4) << 2;
#pragma unroll
  for (int nt = 0; nt < 4; ++nt) {
    const int col = bx * 128 + wn + nt * 16 + l15;
    const float bv = bias[col];
#pragma unroll
    for (int mt = 0; mt < 4; ++mt) {
      const long rowbase = (long)(by * 128 + wm + mt * 16 + rb) * 1536 + col;
#pragma unroll
      for (int v = 0; v < 4; ++v)
        Cf[rowbase + (long)v * 1536] = acc[mt][nt][v] + bv;
    }
  }
}

// fused G3+G4: blocks x<12 -> gi = agg @ w_ih^T + b_ih (split-A);
//              blocks x>=12 -> gh = h @ w_hh^T + b_hh (single)
__global__ __launch_bounds__(256, 3) void gemm_34(
    const f16* __restrict__ agg_hi, const f16* __restrict__ agg_lo,
    const f16* __restrict__ wih, const f16* __restrict__ h_hi,
    const f16* __restrict__ whh, float* __restrict__ gi, float* __restrict__ gh,
    const float* __restrict__ b_ih, const float* __restrict__ b_hh) {
  __shared__ __align__(16) f16 smem[24576];  // 2 x 12288 (SA=1); SA=0 uses 2 x 8192
  const int bx = blockIdx.x, by = blockIdx.y;
  if (bx < 12) gemm_body<1>(agg_hi, agg_lo, wih, gi, b_ih, bx, by, smem);
  else         gemm_body<0>(h_hi, nullptr, whh, gh, b_hh, bx - 12, by, smem);
}

// ---------------- split-K x2 reduce (frag-major): agg = sum_q(Phi+Plo)+bsum ----------------
__global__ void reduce_agg2(const f16* __restrict__ Phi, const f16* __restrict__ Plo,
                            const float* __restrict__ bsum,
                            f16* __restrict__ hi, f16* __restrict__ lo) {
  const long i = ((long)blockIdx.x * blockDim.x + threadIdx.x) * 4;  // 4096x256 blocks
  const int li = (int)i;
  const int l = (li >> 3) & 63, kc = (li >> 9) & 15;
  const int e0 = kc * 32 + ((l >> 4) << 3) + (li & 4);
  const float4 b = *(const float4*)(bsum + e0);
  float v0 = b.x, v1 = b.y, v2 = b.z, v3 = b.w;
#pragma unroll
  for (int q = 0; q < 2; ++q) {
    const long o = (long)q * 4194304 + i;
    const f16x4 ph = *(const f16x4*)(Phi + o);
    const f16x4 pl = *(const f16x4*)(Plo + o);
    v0 += (float)ph.a + (float)pl.a;
    v1 += (float)ph.b + (float)pl.b;
    v2 += (float)ph.c + (float)pl.c;
    v3 += (float)ph.d + (float)pl.d;
  }
  f16x4 h, lw;
  h.a = (f16)v0; lw.a = (f16)(v0 - (float)h.a);
  h.b = (f16)v1; lw.b = (f16)(v1 - (float)h.b);
  h.c = (f16)v2; lw.c = (f16)(v2 - (float)h.c);
  h.d = (f16)v3; lw.d = (f16)(v3 - (float)h.d);
  *(f16x4*)(hi + i) = h;
  *(f16x4*)(lo + i) = lw;
}

// ---------------- GRU elementwise (fp32 gates), h frag-major f16, in-place ----------------
__global__ void gru_k(const float* __restrict__ gi, const float* __restrict__ gh,
                      f16* __restrict__ hhi) {
  const int u = blockIdx.x * blockDim.x + threadIdx.x;  // 524288 threads
  const int row = u >> 6, d0 = (u & 63) << 3;
  const long gbase = (long)row * 1536 + d0;
  const float4 giR0 = *(const float4*)(gi + gbase),      giR1 = *(const float4*)(gi + gbase + 4);
  const float4 giZ0 = *(const float4*)(gi + gbase + 512), giZ1 = *(const float4*)(gi + gbase + 516);
  const float4 giN0 = *(const float4*)(gi + gbase + 1024), giN1 = *(const float4*)(gi + gbase + 1028);
  const float4 ghR0 = *(const float4*)(gh + gbase),      ghR1 = *(const float4*)(gh + gbase + 4);
  const float4 ghZ0 = *(const float4*)(gh + gbase + 512), ghZ1 = *(const float4*)(gh + gbase + 516);
  const float4 ghN0 = *(const float4*)(gh + gbase + 1024), ghN1 = *(const float4*)(gh + gbase + 1028);
  const float irv[8] = {giR0.x, giR0.y, giR0.z, giR0.w, giR1.x, giR1.y, giR1.z, giR1.w};
  const float izv[8] = {giZ0.x, giZ0.y, giZ0.z, giZ0.w, giZ1.x, giZ1.y, giZ1.z, giZ1.w};
  const float inv[8] = {giN0.x, giN0.y, giN0.z, giN0.w, giN1.x, giN1.y, giN1.z, giN1.w};
  const float hrv[8] = {ghR0.x, ghR0.y, ghR0.z, ghR0.w, ghR1.x, ghR1.y, ghR1.z, ghR1.w};
  const float hzv[8] = {ghZ0.x, ghZ0.y, ghZ0.z, ghZ0.w, ghZ1.x, ghZ1.y, ghZ1.z, ghZ1.w};
  const float hnv[8] = {ghN0.x, ghN0.y, ghN0.z, ghN0.w, ghN1.x, ghN1.y, ghN1.z, ghN1.w};
  const long hflat = (long)(row >> 4) * 8192 + (d0 >> 5) * 512 +
                     ((row & 15) + (((d0 >> 3) & 3) << 4)) * 8;
  const half8 hh8 = *(const half8*)(hhi + hflat);  // h (f16; step0: cvt'd nodes)
  half8 oh;
#pragma unroll
  for (int e = 0; e < 8; ++e) {
    const float h = (float)hh8[e];
    const float r = 1.f / (1.f + __expf(-(irv[e] + hrv[e])));
    const float zg = 1.f / (1.f + __expf(-(izv[e] + hzv[e])));
    const float nt = tanhf(inv[e] + r * hnv[e]);
    const float o = (1.f - zg) * nt + zg * h;
    oh[e] = (f16)o;
  }
  *(half8*)(hhi + hflat) = oh;
}

// ---------------- mean over nodes, two-stage (h frag-major) ----------------
__global__ void mean1(const f16* __restrict__ hhi, float* __restrict__ part) {
  const int b = blockIdx.x >> 4, g = blockIdx.x & 15;  // 256 blocks
  const int d = threadIdx.x;                           // 512
  const long base = (long)b * 262144 + (d >> 5) * 512 + (((d >> 3) & 3) << 4) * 8 + (d & 7);
  float s = 0.f;
  for (int n = g * 32; n < g * 32 + 32; ++n) {
    const long j = base + (long)(n >> 4) * 8192 + (n & 15) * 8;
    s += (float)hhi[j];
  }
  part[(long)blockIdx.x * 512 + d] = s;
}
__global__ void mean2(const float* __restrict__ part, float* __restrict__ out) {
  const int b = blockIdx.x;   // 16
  const int d = threadIdx.x;  // 512
  float s = 0.f;
#pragma unroll
  for (int g = 0; g < 16; ++g) s += part[(long)(b * 16 + g) * 512 + d];
  out[b * 512 + d] = s * (1.f / 512.f);
}

extern "C" void kernel_launch(void* const* d_in, const int* in_sizes, int n_in,
                              void* d_out, int out_size, void* d_ws, size_t ws_size,
                              hipStream_t stream) {
  const float* nodes = (const float*)d_in[0];  // [16,512,512]
  const float* edges = (const float*)d_in[1];  // [16,8,512,512]
  const float* msg_W = (const float*)d_in[2];  // [8,512,512]
  const float* msg_b = (const float*)d_in[3];  // [8,512]
  const float* w_ih  = (const float*)d_in[4];  // [1536,512]
  const float* w_hh  = (const float*)d_in[5];  // [1536,512]
  const float* b_ih  = (const float*)d_in[6];  // [1536]
  const float* b_hh  = (const float*)d_in[7];  // [1536]
  float* out = (float*)d_out;                  // [16,512]

  char* ws = (char*)d_ws;
  size_t off = 0;
  auto alloc = [&](size_t bytes) -> char* {
    char* p = ws + off;
    off += (bytes + 1023) & ~(size_t)1023;
    return p;
  };
  f16* edges_hi = (f16*)alloc(33554432ull * 2);  // hi only (edges_lo dropped)
  f16* W_hi     = (f16*)alloc(2097152ull * 2);
  f16* W_lo     = (f16*)alloc(2097152ull * 2);
  f16* wih_hi   = (f16*)alloc(786432ull * 2);
  f16* whh_hi   = (f16*)alloc(786432ull * 2);
  f16* h_hi     = (f16*)alloc(4194304ull * 2);   // hi only (h_lo dropped)
  f16* hWT_hi   = (f16*)alloc(33554432ull * 2);  // head: gi fp32 after G3; tail: agg_hi/lo
  f16* hWT_lo   = (f16*)alloc(33554432ull * 2);  // head: gh fp32 after G4
  f16* Phi      = (f16*)alloc(16777216ull * 2);  // split-K x2 partial hi [q][b][frag-major]
  f16* Plo      = (f16*)alloc(16777216ull * 2);
  float* bsum   = (float*)alloc(512 * 4);
  float* mpart  = (float*)alloc(131072ull * 4);  // mean partials [16*16][512]
  float* gi = (float*)hWT_hi;                 // 50.33 MB
  float* gh = (float*)hWT_lo;                 // 50.33 MB
  f16* agg_hi = hWT_hi + 25165824;            // 8.39 MB
  f16* agg_lo = agg_hi + 4194304;             // 8.39 MB

  // one-time frag-major converts
  cvt_fr1<<<16384, 256, 0, stream>>>(edges, edges_hi, 4194304);
  cvt_fr<<<1024,  256, 0, stream>>>(msg_W, W_hi, W_lo, 262144);
  cvt_fr1_2<<<768, 256, 0, stream>>>(w_ih, wih_hi, w_hh, whh_hi, 98304);
  cvt_fr1<<<2048, 256, 0, stream>>>(nodes, h_hi, 524288);
  bias_sum_k<<<1, 512, 0, stream>>>(msg_b, bsum);

  for (int step = 0; step < 2; ++step) {
    // G1: hWT[b*8+r][e,j] = sum_d W[r][e,d] * h[b][j,d]
    //     split-A (W hi/lo) x single-B (h hi); f16-pair out
    gemm_dr<1, 0, 1, 0><<<dim3(4, 4, 128), 256, 0, stream>>>(
        W_hi, W_lo, h_hi, nullptr, hWT_hi, hWT_lo, nullptr, nullptr,
        512, 1, 0L, 0L, 8, 262144L, 0L, 0L, 262144L, 262144L, 2097152L);
    // G2: split-K x2 (z = b*2+q), R=4, NIT=64; 512 blocks, XCD swizzle
    gemm_dr<0, 1, 1, 1><<<dim3(512, 1, 1), 256, 0, stream>>>(
        edges_hi, nullptr, hWT_hi, hWT_lo, Phi, Plo, nullptr, nullptr,
        512, 4, 262144L, 262144L, 2, 1048576L, 2097152L, 1048576L, 2097152L,
        4194304L, 262144L);
    // reduce: agg = sum_q (Phi+Plo) + bsum -> frag-major hi/lo
    reduce_agg2<<<4096, 256, 0, stream>>>(Phi, Plo, bsum, agg_hi, agg_lo);
    // G3+G4 fused: gi = agg @ w_ih^T + b_ih (split) ; gh = h @ w_hh^T + b_hh
    gemm_34<<<dim3(24, 64), 256, 0, stream>>>(
        agg_hi, agg_lo, wih_hi, h_hi, whh_hi, gi, gh, b_ih, b_hh);
    // GRU update -> h_hi frag-major (in-place; step0 h = cvt'd nodes in h_hi)
    gru_k<<<2048, 256, 0, stream>>>(gi, gh, h_hi);
  }
  mean1<<<256, 512, 0, stream>>>(h_hi, mpart);
  mean2<<<16, 512, 0, stream>>>(mpart, out);
}